// Round 8
// baseline (85.231 us; speedup 1.0000x reference)
//
#include <hip/hip_runtime.h>
#include <hip/hip_bf16.h>
#include <stdint.h>

// ContrastiveLoss — SINGLE fused kernel (R8):
//   d2[b,j,k] = a2[b,j] + b2[b,k] - 2*(A_b . B_b^T)[j,k]
//   loss = sum_{j!=k} [ max(d2,0) + max(1-sqrt(max(d2,0)),0)^2 ] / (B*N*(N-1))
//
// R7 evidence: convert pass (96MB, ~20us) + gemm at 9% MfmaUtil with
// 1 block/CU (no TLP to hide staging/load latency). R8 fuses EVERYTHING:
//   - no bf16 intermediates: A,B read as f32 ONCE (64MB total HBM);
//     cvt f32->bf16 in-flight (v_cvt_pk_bf16_f32 via __float22bfloat162_rn).
//   - BN=64 B-panel (64 rows x 512 K -> 64KB LDS, swizzled bf16) staged
//     once per block from f32; b2 row-sumsq computed during staging.
//   - A streamed f32->reg->bf16 per K-step; a2 accumulated in-register,
//     2 shuffles + per-wave LDS handoff to the epilogue.
//   - 512-thread blocks (8 waves x 64 rows = BM 512), grid 32x16 = 512
//     blocks = 2 blocks/CU (LDS 2x66KB), 16 waves/CU = 4 waves/SIMD.
//   - XCD locality: id = x + 32*y, A-panel sharers (same x, all y) have
//     id%8 = x%8 -> same XCD -> A panel (1MB f32) L2-resident, read 16x.
//   - chunk-XOR swizzle on sB: write slot = (c>>1)^(row&7) (explicit
//     ds_write side), read slot = (ks*4+(lane>>4))^(row&7). Both sides.

#define BATCH 16
#define NDIM  1024
#define DDIM  512
#define BN    64

typedef __attribute__((ext_vector_type(8))) short short8;
typedef __attribute__((ext_vector_type(4))) float floatx4;

union U4S8 { uint32_t u[4]; short8 s; };

__device__ __forceinline__ uint32_t cvt2bf(float lo, float hi) {
    __hip_bfloat162 h = __float22bfloat162_rn(make_float2(lo, hi));
    return *reinterpret_cast<uint32_t*>(&h);
}

// ---------------------------------------------------------------------------
// Fused: stage B(f32->bf16 LDS)+b2, stream A(f32->bf16 reg)+a2, MFMA, loss.
// ---------------------------------------------------------------------------
__global__ __launch_bounds__(512, 4) void pairloss_fused(
    const float* __restrict__ a, const float* __restrict__ b,
    float2* __restrict__ partials) {
    __shared__ ushort sB[BN * DDIM];     // 64KB, swizzled bf16
    __shared__ float b2s[BN];
    __shared__ float a2s[512];
    __shared__ float red[16];

    const int tid  = threadIdx.x;
    const int lane = tid & 63;
    const int wid  = tid >> 6;           // 0..7
    const int bx    = blockIdx.x;        // batch*2 + rowg
    const int colg  = blockIdx.y;        // 0..15
    const int batch = bx >> 1;
    const int rowg  = bx & 1;
    const size_t arow0 = (size_t)batch * NDIM + rowg * 512;
    const size_t brow0 = (size_t)batch * NDIM + colg * BN;

    // ---- stage B panel: wave w handles rows [w*8, w*8+8); per iter one
    // contiguous 1KB of one row (perfect coalescing). f32 16B-chunk c ->
    // bf16 8B at slot (c>>1)^(row&7), half c&1. b2 = rowwise sum x^2. ----
    {
        const float* bsrc = b + brow0 * DDIM;
        float ps[8];
        #pragma unroll
        for (int r = 0; r < 8; ++r) ps[r] = 0.0f;
        #pragma unroll
        for (int i = 0; i < 16; ++i) {
            const int rl  = i >> 1;                // local row 0..7 (static)
            const int c   = (i & 1) * 64 + lane;   // f32 chunk 0..127
            const int row = wid * 8 + rl;          // panel row 0..63
            float4 v = *reinterpret_cast<const float4*>(
                bsrc + (size_t)row * DDIM + c * 4);
            ps[rl] += v.x*v.x + v.y*v.y + v.z*v.z + v.w*v.w;
            uint2 w2 = make_uint2(cvt2bf(v.x, v.y), cvt2bf(v.z, v.w));
            const int slot = (c >> 1) ^ (row & 7);
            *reinterpret_cast<uint2*>(reinterpret_cast<char*>(sB)
                + row * 1024 + slot * 16 + (c & 1) * 8) = w2;
        }
        #pragma unroll
        for (int r = 0; r < 8; ++r) {
            float s = ps[r];
            #pragma unroll
            for (int off = 32; off > 0; off >>= 1) s += __shfl_xor(s, off, 64);
            if (lane == 0) b2s[wid * 8 + r] = s;
        }
    }
    __syncthreads();

    // ---- K-loop: A f32 -> bf16 in-flight, a2 accumulated; B from LDS ----
    const int wrow = wid * 64;
    const float* aRow = a + (arow0 + wrow + (lane & 15)) * DDIM + (lane >> 4) * 8;

    floatx4 acc[4][4];
    #pragma unroll
    for (int m = 0; m < 4; ++m)
        #pragma unroll
        for (int cf = 0; cf < 4; ++cf) acc[m][cf] = 0.0f;
    float a2p[4] = {0.0f, 0.0f, 0.0f, 0.0f};

    #pragma unroll 2
    for (int ks = 0; ks < 16; ++ks) {
        U4S8 am[4];
        #pragma unroll
        for (int m = 0; m < 4; ++m) {
            const float* p = aRow + m * 16 * DDIM + ks * 32;
            float4 v0 = *reinterpret_cast<const float4*>(p);
            float4 v1 = *reinterpret_cast<const float4*>(p + 4);
            a2p[m] += v0.x*v0.x + v0.y*v0.y + v0.z*v0.z + v0.w*v0.w
                    + v1.x*v1.x + v1.y*v1.y + v1.z*v1.z + v1.w*v1.w;
            am[m].u[0] = cvt2bf(v0.x, v0.y);
            am[m].u[1] = cvt2bf(v0.z, v0.w);
            am[m].u[2] = cvt2bf(v1.x, v1.y);
            am[m].u[3] = cvt2bf(v1.z, v1.w);
        }
        #pragma unroll
        for (int cf = 0; cf < 4; ++cf) {
            const int row = cf * 16 + (lane & 15);
            const int cc  = (ks * 4 + (lane >> 4)) ^ (row & 7);
            short8 bv = *reinterpret_cast<const short8*>(&sB[row * DDIM + cc * 8]);
            #pragma unroll
            for (int m = 0; m < 4; ++m)
                acc[m][cf] = __builtin_amdgcn_mfma_f32_16x16x32_bf16(
                    am[m].s, bv, acc[m][cf], 0, 0, 0);
        }
    }

    // ---- a2 handoff: rowsum = sum over 4 chunk-groups (lanes l^16,l^32) ----
    #pragma unroll
    for (int m = 0; m < 4; ++m) {
        float s = a2p[m];
        s += __shfl_xor(s, 16, 64);
        s += __shfl_xor(s, 32, 64);
        if (lane < 16) a2s[wrow + m * 16 + lane] = s;   // same-wave use only
    }

    // ---- epilogue: d2 = a2 + b2 - 2*ab, off-diagonal masked sums ----
    float pos = 0.0f, neg = 0.0f;
    const int rbase = rowg * 512;         // row offset within batch
    const int cbase = colg * BN;          // col offset within batch
    #pragma unroll
    for (int m = 0; m < 4; ++m) {
        const int r0 = wrow + m * 16 + (lane >> 4) * 4;
        #pragma unroll
        for (int cf = 0; cf < 4; ++cf) {
            const int cc = cf * 16 + (lane & 15);
            const float bb = b2s[cc];
            #pragma unroll
            for (int j = 0; j < 4; ++j) {
                const int rr = r0 + j;
                float d2 = a2s[rr] + bb - 2.0f * acc[m][cf][j];
                d2 = fmaxf(d2, 0.0f);
                if (rbase + rr != cbase + cc) {
                    pos += d2;
                    if (d2 < 1.0f) {      // hinge active (rare) -> sqrt here
                        float h = 1.0f - sqrtf(d2);
                        neg += h * h;
                    }
                }
            }
        }
    }

    #pragma unroll
    for (int off = 32; off > 0; off >>= 1) {
        pos += __shfl_xor(pos, off, 64);
        neg += __shfl_xor(neg, off, 64);
    }
    if (lane == 0) { red[wid * 2] = pos; red[wid * 2 + 1] = neg; }
    __syncthreads();
    if (tid == 0) {
        float p = 0.0f, q = 0.0f;
        #pragma unroll
        for (int w = 0; w < 8; ++w) { p += red[w * 2]; q += red[w * 2 + 1]; }
        partials[blockIdx.y * 32 + blockIdx.x] = make_float2(p, q);
    }
}

// ---------------------------------------------------------------------------
// Reduce 512 block partials in double, write scalar loss.
// ---------------------------------------------------------------------------
__global__ __launch_bounds__(256) void finalize_loss(
    const float2* __restrict__ partials, float* __restrict__ out) {
    __shared__ double red[8];
    const int tid = threadIdx.x, lane = tid & 63, wid = tid >> 6;
    double p = 0.0, q = 0.0;
    for (int i = tid; i < 512; i += 256) {
        float2 v = partials[i];
        p += (double)v.x; q += (double)v.y;
    }
    #pragma unroll
    for (int off = 32; off > 0; off >>= 1) {
        p += __shfl_xor(p, off, 64);
        q += __shfl_xor(q, off, 64);
    }
    if (lane == 0) { red[wid * 2] = p; red[wid * 2 + 1] = q; }
    __syncthreads();
    if (tid == 0) {
        double P = red[0] + red[2] + red[4] + red[6];
        double Q = red[1] + red[3] + red[5] + red[7];
        const double n_neg = (double)BATCH * NDIM * (NDIM - 1);
        out[0] = (float)((P + Q) / n_neg);
    }
}

extern "C" void kernel_launch(void* const* d_in, const int* in_sizes, int n_in,
                              void* d_out, int out_size, void* d_ws, size_t ws_size,
                              hipStream_t stream) {
    const float* a = (const float*)d_in[0];
    const float* b = (const float*)d_in[1];
    float* out = (float*)d_out;
    float2* partials = (float2*)d_ws;   // 512 * 8B = 4KB

    // x = batch*2 + rowg (32), y = colg (16): A-panel sharers (same x) have
    // equal (x + 32y) % 8 -> same XCD -> A panel stays L2-resident.
    pairloss_fused<<<dim3(32, 16), 512, 0, stream>>>(a, b, partials);
    finalize_loss<<<1, 256, 0, stream>>>(partials, out);
}

// Round 9
// 62.060 us; speedup vs baseline: 1.3734x; 1.3734x over previous
//
#include <hip/hip_runtime.h>
#include <hip/hip_bf16.h>
#include <stdint.h>

// ContrastiveLoss (R9): convert pass + BN=64 panel-resident GEMM.
//   d2[b,j,k] = a2[b,j] + b2[b,k] - 2*(A_b . B_b^T)[j,k]
//   loss = sum_{j!=k} [ max(d2,0) + max(1-sqrt(max(d2,0)),0)^2 ] / (B*N*(N-1))
//
// R8 lesson: fused f32 streaming throttled VGPRs (64) -> no load pipelining,
// and f32 A-strips (4MB/XCD) + f32 B streams thrashed L2. R9 reverts to the
// measured-good convert pass (bf16 + exact a2/b2) and fixes the GEMM's
// latency-boundness with occupancy:
//   - BN=64 B-panel (64 rows x 512 K = 64KB LDS, swizzled) -> 2 blocks/CU,
//     16 waves/CU = 4 waves/SIMD (R7 had 1 block, 2 waves/SIMD).
//   - zero barriers in K-loop (B resident after one staging barrier).
//   - A streamed bf16 global->reg, 1-step prefetch; per-XCD A residency
//     4 panels x 512KB bf16 = 2MB < 4MB L2; B panels streamed once.
//   - grid 32x16, x = batch*2+rowg: A-panel sharers (same x, all y) have
//     (x+32y)%8 = x%8 -> same XCD.

#define BATCH 16
#define NDIM  1024
#define DDIM  512
#define BN    64

typedef __attribute__((ext_vector_type(8))) short short8;
typedef __attribute__((ext_vector_type(4))) float floatx4;

__device__ __forceinline__ ushort f2bf(float f) {
    uint32_t x = __float_as_uint(f);
    uint32_t r = (x + 0x7FFFu + ((x >> 16) & 1u)) >> 16;  // RNE
    return (ushort)r;
}

// ---------------------------------------------------------------------------
// Pass 1: f32 -> bf16 convert + exact f32 row sum-of-squares. (BW-bound)
// ---------------------------------------------------------------------------
__global__ __launch_bounds__(256) void convert_rowsq(
    const float* __restrict__ a, const float* __restrict__ b,
    ushort* __restrict__ abf, ushort* __restrict__ bbf,
    float* __restrict__ a2, float* __restrict__ b2) {
    const int ROWS = BATCH * NDIM;
    int wid  = blockIdx.x * 4 + (threadIdx.x >> 6);
    int lane = threadIdx.x & 63;
    const float* src; ushort* dst; float* s2; int row;
    if (wid < ROWS) { src = a; dst = abf; s2 = a2; row = wid; }
    else            { src = b; dst = bbf; s2 = b2; row = wid - ROWS; }

    const float4* srow = reinterpret_cast<const float4*>(src + (size_t)row * DDIM);
    float4 v0 = srow[lane];
    float4 v1 = srow[64 + lane];
    float ss = v0.x*v0.x + v0.y*v0.y + v0.z*v0.z + v0.w*v0.w
             + v1.x*v1.x + v1.y*v1.y + v1.z*v1.z + v1.w*v1.w;

    ushort4 u0; u0.x = f2bf(v0.x); u0.y = f2bf(v0.y); u0.z = f2bf(v0.z); u0.w = f2bf(v0.w);
    ushort4 u1; u1.x = f2bf(v1.x); u1.y = f2bf(v1.y); u1.z = f2bf(v1.z); u1.w = f2bf(v1.w);
    ushort* drow = dst + (size_t)row * DDIM;
    *reinterpret_cast<ushort4*>(drow + lane * 4)       = u0;
    *reinterpret_cast<ushort4*>(drow + 256 + lane * 4) = u1;

    #pragma unroll
    for (int off = 32; off > 0; off >>= 1) ss += __shfl_xor(ss, off, 64);
    if (lane == 0) s2[row] = ss;
}

// ---------------------------------------------------------------------------
// Pass 2: BN=64 B-panel-resident MFMA GEMM with fused loss epilogue.
// 512 threads = 8 waves; wave w owns rows [w*64, w*64+64) x all 64 cols.
// ---------------------------------------------------------------------------
__global__ __launch_bounds__(512, 4) void pairloss_gemm(
    const ushort* __restrict__ abf, const ushort* __restrict__ bbf,
    const float* __restrict__ a2, const float* __restrict__ b2,
    float2* __restrict__ partials) {
    __shared__ ushort sB[BN * DDIM];   // 64 KB, chunk-XOR swizzled
    __shared__ float red[16];

    const int tid  = threadIdx.x;
    const int lane = tid & 63;
    const int wid  = tid >> 6;          // 0..7
    const int bx    = blockIdx.x;       // batch*2 + rowg
    const int colg  = blockIdx.y;       // 0..15
    const int batch = bx >> 1;
    const int rowg  = bx & 1;
    const size_t arow0 = (size_t)batch * NDIM + rowg * 512;
    const size_t brow0 = (size_t)batch * NDIM + colg * BN;

    // ---- stage B panel (64 rows x 512 K bf16) once ----
    // 16B chunk q: r = q>>6 (row 0..63), c = q&63. LDS linear dest; source
    // pre-swizzled slot c^(r&7); read uses same XOR. (both-sides, rule 21)
    #pragma unroll 1
    for (int it = 0; it < 8; ++it) {
        const int q = it * 512 + tid;
        const int r = q >> 6, c = q & 63;
        const ushort* src = bbf + (brow0 + r) * DDIM + ((c ^ (r & 7)) << 3);
        __builtin_amdgcn_global_load_lds(
            (const __attribute__((address_space(1))) void*)src,
            (__attribute__((address_space(3))) void*)&sB[(size_t)q * 8], 16, 0, 0);
    }
    asm volatile("s_waitcnt vmcnt(0)" ::: "memory");
    __syncthreads();                    // the ONLY pre-epilogue barrier

    // ---- K-loop: zero barriers; A bf16 global->reg (1-step prefetch) ----
    const int wrow = wid * 64;
    const ushort* aptr = abf + (arow0 + wrow + (lane & 15)) * DDIM + ((lane >> 4) << 3);

    floatx4 acc[4][4];
    #pragma unroll
    for (int m = 0; m < 4; ++m)
        #pragma unroll
        for (int cf = 0; cf < 4; ++cf) acc[m][cf] = 0.0f;

    short8 apre[4];
    #pragma unroll
    for (int m = 0; m < 4; ++m)
        apre[m] = *reinterpret_cast<const short8*>(aptr + m * 16 * DDIM);

    #pragma unroll 1
    for (int ks = 0; ks < 16; ++ks) {
        short8 acur[4];
        #pragma unroll
        for (int m = 0; m < 4; ++m) acur[m] = apre[m];
        if (ks < 15) {
            #pragma unroll
            for (int m = 0; m < 4; ++m)
                apre[m] = *reinterpret_cast<const short8*>(aptr + m * 16 * DDIM + (ks + 1) * 32);
        }
        #pragma unroll
        for (int cf = 0; cf < 4; ++cf) {
            const int row = cf * 16 + (lane & 15);               // row&7 == lane&7
            const int cc  = (ks * 4 + (lane >> 4)) ^ (lane & 7); // swizzled chunk
            short8 bv = *reinterpret_cast<const short8*>(&sB[row * DDIM + cc * 8]);
            #pragma unroll
            for (int m = 0; m < 4; ++m)
                acc[m][cf] = __builtin_amdgcn_mfma_f32_16x16x32_bf16(acur[m], bv, acc[m][cf], 0, 0, 0);
        }
    }

    // ---- epilogue: d2 = a2[row] + b2[col] - 2*ab, off-diag masked sums ----
    float pos = 0.0f, neg = 0.0f;
    const float* a2p = a2 + arow0 + wrow;
    const float* b2p = b2 + brow0;
    const int rbase = rowg * 512 + wrow;  // row offset within batch
    const int cbase = colg * BN;          // col offset within batch
    #pragma unroll
    for (int m = 0; m < 4; ++m) {
        const int r0 = m * 16 + (lane >> 4) * 4;
        #pragma unroll
        for (int cf = 0; cf < 4; ++cf) {
            const int cc = cf * 16 + (lane & 15);
            const float bb = b2p[cc];
            #pragma unroll
            for (int j = 0; j < 4; ++j) {
                const int rr = r0 + j;
                float d2 = a2p[rr] + bb - 2.0f * acc[m][cf][j];
                d2 = fmaxf(d2, 0.0f);
                if (rbase + rr != cbase + cc) {
                    pos += d2;
                    if (d2 < 1.0f) {      // hinge active (rare) -> sqrt here
                        float h = 1.0f - sqrtf(d2);
                        neg += h * h;
                    }
                }
            }
        }
    }

    #pragma unroll
    for (int off = 32; off > 0; off >>= 1) {
        pos += __shfl_xor(pos, off, 64);
        neg += __shfl_xor(neg, off, 64);
    }
    if (lane == 0) { red[wid * 2] = pos; red[wid * 2 + 1] = neg; }
    __syncthreads();
    if (tid == 0) {
        float p = 0.0f, q = 0.0f;
        #pragma unroll
        for (int w = 0; w < 8; ++w) { p += red[w * 2]; q += red[w * 2 + 1]; }
        partials[blockIdx.y * 32 + blockIdx.x] = make_float2(p, q);
    }
}

// ---------------------------------------------------------------------------
// Pass 3: reduce 512 block partials in double, write scalar loss.
// ---------------------------------------------------------------------------
__global__ __launch_bounds__(256) void finalize_loss(
    const float2* __restrict__ partials, float* __restrict__ out) {
    __shared__ double red[8];
    const int tid = threadIdx.x, lane = tid & 63, wid = tid >> 6;
    double p = 0.0, q = 0.0;
    for (int i = tid; i < 512; i += 256) {
        float2 v = partials[i];
        p += (double)v.x; q += (double)v.y;
    }
    #pragma unroll
    for (int off = 32; off > 0; off >>= 1) {
        p += __shfl_xor(p, off, 64);
        q += __shfl_xor(q, off, 64);
    }
    if (lane == 0) { red[wid * 2] = p; red[wid * 2 + 1] = q; }
    __syncthreads();
    if (tid == 0) {
        double P = red[0] + red[2] + red[4] + red[6];
        double Q = red[1] + red[3] + red[5] + red[7];
        const double n_neg = (double)BATCH * NDIM * (NDIM - 1);
        out[0] = (float)((P + Q) / n_neg);
    }
}

extern "C" void kernel_launch(void* const* d_in, const int* in_sizes, int n_in,
                              void* d_out, int out_size, void* d_ws, size_t ws_size,
                              hipStream_t stream) {
    const float* a = (const float*)d_in[0];
    const float* b = (const float*)d_in[1];
    float* out = (float*)d_out;

    const size_t NELEM = (size_t)BATCH * NDIM * DDIM;   // 8,388,608
    ushort* abf = (ushort*)d_ws;
    ushort* bbf = abf + NELEM;
    float*  a2  = (float*)(bbf + NELEM);
    float*  b2  = a2 + BATCH * NDIM;
    float2* partials = (float2*)(b2 + BATCH * NDIM);

    convert_rowsq<<<(2 * BATCH * NDIM) / 4, 256, 0, stream>>>(a, b, abf, bbf, a2, b2);

    // x = batch*2 + rowg (32), y = colg (16): A-panel sharers (same x) have
    // equal (x+32y)%8 -> same XCD -> A panel (512KB bf16) L2-resident.
    pairloss_gemm<<<dim3(32, 16), 512, 0, stream>>>(abf, bbf, a2, b2, partials);

    finalize_loss<<<1, 256, 0, stream>>>(partials, out);
}

// Round 10
// 47.456 us; speedup vs baseline: 1.7960x; 1.3077x over previous
//
#include <hip/hip_runtime.h>
#include <hip/hip_bf16.h>
#include <stdint.h>

// ContrastiveLoss (R10): convert pass + 256x256-tile deep-pipelined GEMM.
//   d2[b,j,k] = a2[b,j] + b2[b,k] - 2*(A_b . B_b^T)[j,k]
//   loss = sum_{j!=k} [ max(d2,0) + max(1-sqrt(max(d2,0)),0)^2 ] / (B*N*(N-1))
//
// Evidence R1-R9: every shallow structure = 235-570 TF. R10 adopts the
// m201-class 256^2 template: 8 waves (2x4), BK=64 (8 K-tiles), LDS
// [2][2][256][64] dbuf (128KB), global_load_lds staging w/ both-sides XOR
// swizzle, counted s_waitcnt vmcnt(8) (never 0 mid-loop), setprio on MFMA.
// Grid 16x4x4 = 256 blocks = 1/CU; id = batch + 16*colt + 64*rowt -> each
// batch's 16 blocks share an XCD (A,B panels L2-resident, ~4MB/XCD).

#define BATCH 16
#define NDIM  1024
#define DDIM  512

typedef __attribute__((ext_vector_type(8))) short short8;
typedef __attribute__((ext_vector_type(4))) float floatx4;

__device__ __forceinline__ ushort f2bf(float f) {
    uint32_t x = __float_as_uint(f);
    uint32_t r = (x + 0x7FFFu + ((x >> 16) & 1u)) >> 16;  // RNE
    return (ushort)r;
}

// ---------------------------------------------------------------------------
// Pass 1: f32 -> bf16 convert + exact f32 row sum-of-squares. (BW-bound)
// ---------------------------------------------------------------------------
__global__ __launch_bounds__(256) void convert_rowsq(
    const float* __restrict__ a, const float* __restrict__ b,
    ushort* __restrict__ abf, ushort* __restrict__ bbf,
    float* __restrict__ a2, float* __restrict__ b2) {
    const int ROWS = BATCH * NDIM;
    int wid  = blockIdx.x * 4 + (threadIdx.x >> 6);
    int lane = threadIdx.x & 63;
    const float* src; ushort* dst; float* s2; int row;
    if (wid < ROWS) { src = a; dst = abf; s2 = a2; row = wid; }
    else            { src = b; dst = bbf; s2 = b2; row = wid - ROWS; }

    const float4* srow = reinterpret_cast<const float4*>(src + (size_t)row * DDIM);
    float4 v0 = srow[lane];
    float4 v1 = srow[64 + lane];
    float ss = v0.x*v0.x + v0.y*v0.y + v0.z*v0.z + v0.w*v0.w
             + v1.x*v1.x + v1.y*v1.y + v1.z*v1.z + v1.w*v1.w;

    ushort4 u0; u0.x = f2bf(v0.x); u0.y = f2bf(v0.y); u0.z = f2bf(v0.z); u0.w = f2bf(v0.w);
    ushort4 u1; u1.x = f2bf(v1.x); u1.y = f2bf(v1.y); u1.z = f2bf(v1.z); u1.w = f2bf(v1.w);
    ushort* drow = dst + (size_t)row * DDIM;
    *reinterpret_cast<ushort4*>(drow + lane * 4)       = u0;
    *reinterpret_cast<ushort4*>(drow + 256 + lane * 4) = u1;

    #pragma unroll
    for (int off = 32; off > 0; off >>= 1) ss += __shfl_xor(ss, off, 64);
    if (lane == 0) s2[row] = ss;
}

// ---------------------------------------------------------------------------
// Pass 2: 256x256-tile MFMA GEMM, dbuf counted-vmcnt pipeline, fused loss.
// 8 waves as 2x4; wave out = 128x64 = 8m x 4cf frags of 16x16.
// ---------------------------------------------------------------------------
__global__ __launch_bounds__(512, 2) void pairloss_gemm(
    const ushort* __restrict__ abf, const ushort* __restrict__ bbf,
    const float* __restrict__ a2, const float* __restrict__ b2,
    float2* __restrict__ partials) {
    __shared__ ushort sAB[2][2][256][64];   // [buf][op][row][col] = 128 KB
    __shared__ float red[16];

    const int tid  = threadIdx.x;
    const int lane = tid & 63;
    const int wid  = tid >> 6;              // 0..7
    const int batch = blockIdx.x;           // 0..15
    const int colt  = blockIdx.y;           // 0..3
    const int rowt  = blockIdx.z;           // 0..3
    const size_t arow0 = (size_t)batch * NDIM + rowt * 256;
    const size_t brow0 = (size_t)batch * NDIM + colt * 256;

    // Stage tile kt (A 256x64 + B 256x64 bf16 = 64KB) into buf p.
    // 8 loads/thread; load i: q = i*512+tid; op=q>>11; row=(q&2047)>>3;
    // slot=q&7. LDS linear dest; source chunk pre-swizzled slot^(row&7);
    // read uses the same XOR (both-sides, rule 21).
    auto stage = [&](int p, int kt) {
        #pragma unroll
        for (int i = 0; i < 8; ++i) {
            const int q    = i * 512 + tid;
            const int op   = q >> 11;                // 0..3 -> A, 4..7 -> B
            const int row  = (q & 2047) >> 3;
            const int slot = q & 7;
            const int gcol = kt * 64 + ((slot ^ (row & 7)) << 3);
            const ushort* src = (op ? bbf + (brow0 + row) * DDIM + gcol
                                    : abf + (arow0 + row) * DDIM + gcol);
            __builtin_amdgcn_global_load_lds(
                (const __attribute__((address_space(1))) void*)src,
                (__attribute__((address_space(3))) void*)&sAB[p][op][row][slot * 8],
                16, 0, 0);
        }
    };

    floatx4 acc[8][4];
    #pragma unroll
    for (int m = 0; m < 8; ++m)
        #pragma unroll
        for (int cf = 0; cf < 4; ++cf) acc[m][cf] = 0.0f;

    const int wr = (wid >> 2) * 128;        // wave row base in tile
    const int wc = (wid & 3) * 64;          // wave col base in tile

    stage(0, 0);
    stage(1, 1);
    asm volatile("s_waitcnt vmcnt(8)" ::: "memory");   // T0 landed (T1 in flight)
    __builtin_amdgcn_s_barrier();
    __builtin_amdgcn_sched_barrier(0);

    #pragma unroll 1
    for (int kt = 0; kt < 8; ++kt) {
        const int p = kt & 1;
        #pragma unroll
        for (int kk = 0; kk < 2; ++kk) {
            short8 af[8], bfr[4];
            #pragma unroll
            for (int m = 0; m < 8; ++m) {
                const int row  = wr + m * 16 + (lane & 15);
                const int slot = (kk * 4 + (lane >> 4)) ^ (row & 7);
                af[m] = *reinterpret_cast<const short8*>(&sAB[p][0][row][slot * 8]);
            }
            #pragma unroll
            for (int cf = 0; cf < 4; ++cf) {
                const int row  = wc + cf * 16 + (lane & 15);
                const int slot = (kk * 4 + (lane >> 4)) ^ (row & 7);
                bfr[cf] = *reinterpret_cast<const short8*>(&sAB[p][1][row][slot * 8]);
            }
            __builtin_amdgcn_s_setprio(1);
            #pragma unroll
            for (int m = 0; m < 8; ++m)
                #pragma unroll
                for (int cf = 0; cf < 4; ++cf)
                    acc[m][cf] = __builtin_amdgcn_mfma_f32_16x16x32_bf16(
                        af[m], bfr[cf], acc[m][cf], 0, 0, 0);
            __builtin_amdgcn_s_setprio(0);
        }
        __builtin_amdgcn_s_barrier();           // all waves done reading buf p
        __builtin_amdgcn_sched_barrier(0);
        if (kt + 2 < 8) stage(p, kt + 2);       // refill freed buffer (async)
        if (kt + 1 < 8) {
            if (kt + 2 < 8) asm volatile("s_waitcnt vmcnt(8)" ::: "memory"); // T_{kt+1} landed
            else            asm volatile("s_waitcnt vmcnt(0)" ::: "memory");
            __builtin_amdgcn_s_barrier();
            __builtin_amdgcn_sched_barrier(0);
        }
    }

    // ---- epilogue: d2 = a2[row] + b2[col] - 2*ab, off-diag masked sums ----
    float pos = 0.0f, neg = 0.0f;
    const float* a2p = a2 + arow0;
    const float* b2p = b2 + brow0;
    const int rbase = rowt * 256;           // row offset within batch
    const int cbase = colt * 256;           // col offset within batch
    #pragma unroll
    for (int m = 0; m < 8; ++m) {
        const int r0 = wr + m * 16 + (lane >> 4) * 4;
        #pragma unroll
        for (int cf = 0; cf < 4; ++cf) {
            const int cc = wc + cf * 16 + (lane & 15);
            const float bb = b2p[cc];
            #pragma unroll
            for (int j = 0; j < 4; ++j) {
                const int rr = r0 + j;
                float d2 = a2p[rr] + bb - 2.0f * acc[m][cf][j];
                d2 = fmaxf(d2, 0.0f);
                if (rbase + rr != cbase + cc) {
                    pos += d2;
                    if (d2 < 1.0f) {        // hinge active (rare) -> sqrt here
                        float h = 1.0f - sqrtf(d2);
                        neg += h * h;
                    }
                }
            }
        }
    }

    #pragma unroll
    for (int off = 32; off > 0; off >>= 1) {
        pos += __shfl_xor(pos, off, 64);
        neg += __shfl_xor(neg, off, 64);
    }
    if (lane == 0) { red[wid * 2] = pos; red[wid * 2 + 1] = neg; }
    __syncthreads();
    if (tid == 0) {
        float p = 0.0f, q = 0.0f;
        #pragma unroll
        for (int w = 0; w < 8; ++w) { p += red[w * 2]; q += red[w * 2 + 1]; }
        const int bidx = (blockIdx.z * 4 + blockIdx.y) * 16 + blockIdx.x;
        partials[bidx] = make_float2(p, q);
    }
}

// ---------------------------------------------------------------------------
// Pass 3: reduce 256 block partials in double, write scalar loss.
// ---------------------------------------------------------------------------
__global__ __launch_bounds__(256) void finalize_loss(
    const float2* __restrict__ partials, float* __restrict__ out) {
    __shared__ double red[8];
    const int tid = threadIdx.x, lane = tid & 63, wid = tid >> 6;
    double p = 0.0, q = 0.0;
    for (int i = tid; i < 256; i += 256) {
        float2 v = partials[i];
        p += (double)v.x; q += (double)v.y;
    }
    #pragma unroll
    for (int off = 32; off > 0; off >>= 1) {
        p += __shfl_xor(p, off, 64);
        q += __shfl_xor(q, off, 64);
    }
    if (lane == 0) { red[wid * 2] = p; red[wid * 2 + 1] = q; }
    __syncthreads();
    if (tid == 0) {
        double P = red[0] + red[2] + red[4] + red[6];
        double Q = red[1] + red[3] + red[5] + red[7];
        const double n_neg = (double)BATCH * NDIM * (NDIM - 1);
        out[0] = (float)((P + Q) / n_neg);
    }
}

extern "C" void kernel_launch(void* const* d_in, const int* in_sizes, int n_in,
                              void* d_out, int out_size, void* d_ws, size_t ws_size,
                              hipStream_t stream) {
    const float* a = (const float*)d_in[0];
    const float* b = (const float*)d_in[1];
    float* out = (float*)d_out;

    const size_t NELEM = (size_t)BATCH * NDIM * DDIM;   // 8,388,608
    ushort* abf = (ushort*)d_ws;
    ushort* bbf = abf + NELEM;
    float*  a2  = (float*)(bbf + NELEM);
    float*  b2  = a2 + BATCH * NDIM;
    float2* partials = (float2*)(b2 + BATCH * NDIM);

    convert_rowsq<<<(2 * BATCH * NDIM) / 4, 256, 0, stream>>>(a, b, abf, bbf, a2, b2);

    // x=batch, y=colt, z=rowt: id = x + 16y + 64z -> id%8 = batch%8, so each
    // batch's 16 tile-blocks share an XCD (A,B bf16 panels L2-resident).
    pairloss_gemm<<<dim3(16, 4, 4), 512, 0, stream>>>(abf, bbf, a2, b2, partials);

    finalize_loss<<<1, 256, 0, stream>>>(partials, out);
}